// Round 9
// baseline (121.247 us; speedup 1.0000x reference)
//
#include <hip/hip_runtime.h>

// ============================================================================
// 7-layer MLP (3->40x6->3, tanh) via f16 MFMA + dual-pipe tanh, 128 pts/wave.
//
// r8 postmortem: trans ops (v_exp/v_rcp) issue-block the VALU port ~16cyc
// each (no co-issue; r3+r8 counter fit). Per-tanh cost: exp path 37 cyc VALU;
// table path 10 cyc VALU + 5.8 cyc LDS (parallel pipe). Joint optimum at
// SEXP=3 (words 0..2 exp = 12/40 neurons, rest table) with 4 B-tiles/wave
// (frag ds_read_b128s amortized 4x): VALU ~66us, LDS ~63us, balanced.
//
// MFMA layout contracts (gfx950 v_mfma_f32_32x32x16_f16), verified r3-r8:
//   A: row = lane&31, k = 8*(lane>>5)+i   B: col = lane&31, same k packing
//   D: col = lane&31, row = (reg&3) + 8*(reg>>2) + 4*(lane>>5)
// K-columns permuted (kappa) so D->B repack is in-lane. Verified identity:
// P := 4*(kap>>4) + ((kap&7)>>1) == Bf word index, all 40 neurons -> prep's
// per-row path split (P < SEXP) matches ACT's static word split.
// Exp rows pre-scaled 2/ln2 (MFMA emits y; tanh = 1-2*rcp(1+2^y), exact).
// Table rows pre-scaled 32 + offset col 112 (MFMA emits u = (x+3.5)*32).
// Table: 225 entries, packed f16 {base,delta}/u32, 32-replica in LDS ->
// bank == lane&31 -> conflict-free (verified r7: conflicts 1.6e7 -> 0).
// ws = 36.7 KB total (r6 ERRATA: 64.6 KB overflowed ws, poisoned table tail).
// ============================================================================

typedef _Float16 f16x8 __attribute__((ext_vector_type(8)));
typedef float    f32x16 __attribute__((ext_vector_type(16)));
typedef unsigned int u32x4 __attribute__((ext_vector_type(4)));

#define NFRAG  35        // L0: 2, L1..5: 6 each, L6: 3
#define TABN   225       // entries, domain [-3.5, 3.5], h = 1/32
#define TABREP 32        // LDS replication -> bank = lane&31, conflict-free
#define SEXP   3         // Bf words 0..2 (12 rows/layer) via exp path
#define INVH   32.0f
#define UOFF   112.0f    // 3.5*32, exact in f16
#define UMAX   223.999f
#define TABR   3.5f
#define EXPSC  2.8853900817779268f   // 2/ln(2)

// k-slot -> input neuron; -2 = bias, -3 = offset const, -1 = zero pad
__constant__ int INV[48] = {
     0,  1,  2,  3,   8,  9, 10, 11,   4,  5,  6,  7,  12, 13, 14, 15,
    16, 17, 18, 19,  24, 25, 26, 27,  20, 21, 22, 23,  28, 29, 30, 31,
    32, 33, 34, 35,  -1, -1, -1, -1,  36, 37, 38, 39,  -2, -3, -1, -1 };

// output neuron j -> k-slot (kappa); P(j) = 4*(kap>>4) + ((kap&7)>>1) = word
__constant__ int KAP[40] = {
     0,  1,  2,  3,   8,  9, 10, 11,   4,  5,  6,  7,  12, 13, 14, 15,
    16, 17, 18, 19,  24, 25, 26, 27,  20, 21, 22, 23,  28, 29, 30, 31,
    32, 33, 34, 35,  40, 41, 42, 43 };

__global__ void prep_frags(const float* __restrict__ W0, const float* __restrict__ b0,
                           const float* __restrict__ W1, const float* __restrict__ b1,
                           const float* __restrict__ W2, const float* __restrict__ b2,
                           const float* __restrict__ W3, const float* __restrict__ b3,
                           const float* __restrict__ W4, const float* __restrict__ b4,
                           const float* __restrict__ W5, const float* __restrict__ b5,
                           const float* __restrict__ W6, const float* __restrict__ b6,
                           unsigned short* __restrict__ frags,
                           unsigned* __restrict__ table)
{
    int tid = blockIdx.x * 256 + threadIdx.x;

    if (tid < NFRAG * 64) {
        int frag = tid >> 6, lane = tid & 63;

        int layer, mt, ch;
        if (frag < 2)       { layer = 0; mt = frag; ch = 0; }
        else if (frag < 32) { int t = frag - 2; layer = 1 + t / 6; int r = t % 6; mt = r / 3; ch = r % 3; }
        else                { layer = 6; mt = 0; ch = frag - 32; }

        const float* Ws[7] = { W0, W1, W2, W3, W4, W5, W6 };
        const float* bs[7] = { b0, b1, b2, b3, b4, b5, b6 };
        const float* W = Ws[layer];
        const float* b = bs[layer];
        const int fout = (layer == 6) ? 3 : 40;

        int jout  = mt * 32 + (lane & 31);
        int kbase = ch * 16 + (lane >> 5) * 8;

        unsigned short h[8];
        for (int i = 0; i < 8; ++i) {
            int k = kbase + i;
            float v = 0.0f;
            if (jout < fout) {
                int jin;
                if (layer == 0) jin = (k < 3) ? k : ((k == 3) ? -2 : ((k == 4) ? -3 : -1));
                else            jin = INV[k];
                bool ex = false;
                if (layer < 6) {
                    int kp = KAP[jout];
                    int P = 4 * (kp >> 4) + ((kp & 7) >> 1);   // == Bf word index
                    ex = (P < SEXP);
                }
                float scale = (layer == 6) ? 1.0f : (ex ? EXPSC : INVH);
                if (jin >= 0)       v = W[jin * fout + jout] * scale;
                else if (jin == -2) v = b[jout] * scale;
                else if (jin == -3) v = (layer == 6 || ex) ? 0.0f : UOFF;
            }
            _Float16 hv = (_Float16)v;
            h[i] = __builtin_bit_cast(unsigned short, hv);
        }
        unsigned short* dst = frags + frag * 512 + lane * 8;
        for (int i = 0; i < 8; ++i) dst[i] = h[i];
    }
    else if (tid < NFRAG * 64 + TABN) {
        int i = tid - NFRAG * 64;
        const float H = 1.0f / 32.0f;
        float x  = -TABR + (float)i * H;
        float t0 = tanhf(x);
        float t1 = tanhf(x + H);
        float MID = 0.5f * (1.0f + tanhf(TABR));
        float base = t0, delta = t1 - t0;
        if (i == 0)        { base = -MID; delta = t1 - base; }   // left clamp midpoint
        if (i == TABN - 2) { delta = MID - t0; }                 // right clamp midpoint
        unsigned short bb = __builtin_bit_cast(unsigned short, (_Float16)base);
        unsigned short dd = __builtin_bit_cast(unsigned short, (_Float16)delta);
        table[i] = (unsigned)bb | ((unsigned)dd << 16);          // unreplicated, 900 B
    }
}

__device__ __forceinline__ unsigned int pkf16(float a, float b) {
    return __builtin_bit_cast(unsigned int, __builtin_amdgcn_cvt_pkrtz(a, b));
}
__device__ __forceinline__ f32x16 zf() {
    f32x16 v;
    #pragma unroll
    for (int i = 0; i < 16; ++i) v[i] = 0.0f;
    return v;
}
__device__ __forceinline__ float exp2_fast(float y) {
#if __has_builtin(__builtin_amdgcn_exp2f)
    return __builtin_amdgcn_exp2f(y);
#else
    float e;
    asm("v_exp_f32 %0, %1" : "=v"(e) : "v"(y));
    return e;
#endif
}

#define MFMA __builtin_amdgcn_mfma_f32_32x32x16_f16

// words 0..2: exp path (y = 2x/ln2 from MFMA); words 3..9: table path
#define ACT(Da, Db, Bfx) do {                         \
    Bfx[0]  = pkf16(te(Da[0]),  te(Da[1]));           \
    Bfx[1]  = pkf16(te(Da[2]),  te(Da[3]));           \
    Bfx[2]  = pkf16(te(Da[4]),  te(Da[5]));           \
    Bfx[3]  = tl2(Da[6],  Da[7]);                     \
    Bfx[4]  = tl2(Da[8],  Da[9]);                     \
    Bfx[5]  = tl2(Da[10], Da[11]);                    \
    Bfx[6]  = tl2(Da[12], Da[13]);                    \
    Bfx[7]  = tl2(Da[14], Da[15]);                    \
    Bfx[8]  = tl2(Db[0],  Db[1]);                     \
    Bfx[9]  = tl2(Db[2],  Db[3]);                     \
    Bfx[10] = PK11;                                   \
    Bfx[11] = 0u;                                     \
} while (0)

// one 32-point tile of layer 0 (K chunk 0: coords + bias + offset cols)
#define L0_TILE(Bfx) do {                             \
    f16x8 bb = BFx(Bfx, 0);                           \
    f32x16 D0 = MFMA(F0, bb, CZ, 0, 0, 0);            \
    f32x16 D1 = MFMA(F1, bb, CZ, 0, 0, 0);            \
    ACT(D0, D1, Bfx);                                 \
} while (0)

// one 32-point tile of a hidden layer
#define HID_TILE(Bfx) do {                            \
    f16x8 B0 = BFx(Bfx, 0), B1 = BFx(Bfx, 1), B2 = BFx(Bfx, 2); \
    f32x16 D0 = MFMA(F0, B0, CZ, 0, 0, 0);            \
    D0 = MFMA(F1, B1, D0, 0, 0, 0);                   \
    D0 = MFMA(F2, B2, D0, 0, 0, 0);                   \
    f32x16 D1 = MFMA(F3, B0, CZ, 0, 0, 0);            \
    D1 = MFMA(F4, B1, D1, 0, 0, 0);                   \
    D1 = MFMA(F5, B2, D1, 0, 0, 0);                   \
    ACT(D0, D1, Bfx);                                 \
} while (0)

// one 32-point tile of the final layer (rows 0..2, lane<32)
#define FIN_TILE(Bfx, pX, vX) do {                    \
    f32x16 D0 = MFMA(F0, BFx(Bfx, 0), CZ, 0, 0, 0);   \
    D0 = MFMA(F1, BFx(Bfx, 1), D0, 0, 0, 0);          \
    D0 = MFMA(F2, BFx(Bfx, 2), D0, 0, 0, 0);          \
    if (lane < 32 && vX) {                            \
        out[(pX) * 3 + 0] = D0[0];                    \
        out[(pX) * 3 + 1] = D0[1];                    \
        out[(pX) * 3 + 2] = D0[2];                    \
    }                                                 \
} while (0)

__global__ __launch_bounds__(512, 4) void mlp_mfma(const float* __restrict__ coords,
                                                   const unsigned short* __restrict__ frags,
                                                   const unsigned* __restrict__ gtab,
                                                   float* __restrict__ out, int npts)
{
    __shared__ __align__(16) unsigned short sf[NFRAG * 512];   // 35840 B
    __shared__ __align__(16) unsigned stab[TABN * TABREP];     // 28800 B
    {
        const u32x4* s1 = (const u32x4*)frags; u32x4* d1 = (u32x4*)sf;
        for (int i = threadIdx.x; i < NFRAG * 64; i += 512) d1[i] = s1[i];
        // replicate 32x from the unreplicated global table (L2-resident)
        for (int i = threadIdx.x; i < TABN * TABREP; i += 512) stab[i] = gtab[i >> 5];
    }
    __syncthreads();

    const int lane = threadIdx.x & 63;
    const int wid  = threadIdx.x >> 6;
    const int pA   = (blockIdx.x * 8 + wid) * 128 + (lane & 31);
    const int pB   = pA + 32;
    const int pC   = pA + 64;
    const int pD   = pA + 96;
    const bool vA = (pA < npts), vB = (pB < npts), vC = (pC < npts), vD = (pD < npts);

    const unsigned int PK11 = pkf16(1.0f, 1.0f);
    const unsigned* __restrict__ tb = stab + (lane & 31);   // bank = lane&31 always
    const f32x16 CZ = zf();

    // table path: u = (x+3.5)*32 from MFMA; {base,delta} packed f16 in u32.
    auto tl2 = [&](float ua, float ub) -> unsigned {
        ua = __builtin_amdgcn_fmed3f(ua, 0.0f, UMAX);
        ub = __builtin_amdgcn_fmed3f(ub, 0.0f, UMAX);
        float fa = __builtin_amdgcn_fractf(ua);
        float fb = __builtin_amdgcn_fractf(ub);
        unsigned ea = tb[(unsigned)ua * TABREP];   // ds_read_b32, conflict-free
        unsigned eb = tb[(unsigned)ub * TABREP];
        unsigned r;
        asm("v_fma_mixlo_f16 %0, %1, %2, %2 op_sel:[0,1,0] op_sel_hi:[0,1,1]"
            : "=v"(r) : "v"(fa), "v"(ea));
        asm("v_fma_mixhi_f16 %0, %1, %2, %2 op_sel:[0,1,0] op_sel_hi:[0,1,1]"
            : "+v"(r) : "v"(fb), "v"(eb));
        return r;
    };
    // exp path: y = 2x/ln2 from MFMA; tanh = 1 - 2/(1+2^y). Exact, no clamp.
    auto te = [&](float y) -> float {
        float e = exp2_fast(y);
        float r = __builtin_amdgcn_rcpf(e + 1.0f);
        return __builtin_fmaf(-2.0f, r, 1.0f);
    };

    unsigned int BfA[12], BfB[12], BfC[12], BfD[12];
    {
        float a0 = 0.f, a1 = 0.f, a2 = 0.f, b0 = 0.f, b1 = 0.f, b2 = 0.f;
        float c0 = 0.f, c1 = 0.f, c2 = 0.f, d0 = 0.f, d1 = 0.f, d2 = 0.f;
        if (vA) { a0 = coords[pA * 3]; a1 = coords[pA * 3 + 1]; a2 = coords[pA * 3 + 2]; }
        if (vB) { b0 = coords[pB * 3]; b1 = coords[pB * 3 + 1]; b2 = coords[pB * 3 + 2]; }
        if (vC) { c0 = coords[pC * 3]; c1 = coords[pC * 3 + 1]; c2 = coords[pC * 3 + 2]; }
        if (vD) { d0 = coords[pD * 3]; d1 = coords[pD * 3 + 1]; d2 = coords[pD * 3 + 2]; }
        BfA[0] = pkf16(a0, a1); BfA[1] = pkf16(a2, 1.0f);
        BfB[0] = pkf16(b0, b1); BfB[1] = pkf16(b2, 1.0f);
        BfC[0] = pkf16(c0, c1); BfC[1] = pkf16(c2, 1.0f);
        BfD[0] = pkf16(d0, d1); BfD[1] = pkf16(d2, 1.0f);
        BfA[2] = BfB[2] = BfC[2] = BfD[2] = pkf16(1.0f, 0.0f);
        BfA[3] = BfB[3] = BfC[3] = BfD[3] = 0u;
    }

    auto AF = [&](int f) -> f16x8 {
        return ((const f16x8*)sf)[f * 64 + lane];
    };
    auto BFx = [&](const unsigned (&B)[12], int c) -> f16x8 {
        u32x4 t = { B[4 * c + 0], B[4 * c + 1], B[4 * c + 2], B[4 * c + 3] };
        return __builtin_bit_cast(f16x8, t);
    };

    f16x8 F0, F1, F2, F3, F4, F5;

    // ---- layer 0
    F0 = AF(0); F1 = AF(1);
    L0_TILE(BfA); L0_TILE(BfB); L0_TILE(BfC); L0_TILE(BfD);

    // ---- hidden layers 1..5
    #pragma unroll
    for (int l = 1; l <= 5; ++l) {
        const int fb = 2 + (l - 1) * 6;
        F0 = AF(fb + 0); F1 = AF(fb + 1); F2 = AF(fb + 2);
        F3 = AF(fb + 3); F4 = AF(fb + 4); F5 = AF(fb + 5);
        HID_TILE(BfA); HID_TILE(BfB); HID_TILE(BfC); HID_TILE(BfD);
    }

    // ---- layer 6: [40] -> [3], true scale, no tanh
    F0 = AF(32); F1 = AF(33); F2 = AF(34);
    FIN_TILE(BfA, pA, vA);
    FIN_TILE(BfB, pB, vB);
    FIN_TILE(BfC, pC, vC);
    FIN_TILE(BfD, pD, vD);
}

extern "C" void kernel_launch(void* const* d_in, const int* in_sizes, int n_in,
                              void* d_out, int out_size, void* d_ws, size_t ws_size,
                              hipStream_t stream)
{
    const float* coords = (const float*)d_in[0];
    const float* W0 = (const float*)d_in[1];  const float* b0 = (const float*)d_in[2];
    const float* W1 = (const float*)d_in[3];  const float* b1 = (const float*)d_in[4];
    const float* W2 = (const float*)d_in[5];  const float* b2 = (const float*)d_in[6];
    const float* W3 = (const float*)d_in[7];  const float* b3 = (const float*)d_in[8];
    const float* W4 = (const float*)d_in[9];  const float* b4 = (const float*)d_in[10];
    const float* W5 = (const float*)d_in[11]; const float* b5 = (const float*)d_in[12];
    const float* W6 = (const float*)d_in[13]; const float* b6 = (const float*)d_in[14];
    float* out = (float*)d_out;

    unsigned short* frags = (unsigned short*)d_ws;                      // 35840 B
    unsigned* table = (unsigned*)((char*)d_ws + NFRAG * 1024);          // 900 B

    const int npts = in_sizes[0] / 3;

    const int prep_threads = NFRAG * 64 + TABN;
    prep_frags<<<(prep_threads + 255) / 256, 256, 0, stream>>>(
        W0, b0, W1, b1, W2, b2, W3, b3, W4, b4, W5, b5, W6, b6, frags, table);

    const int blocks = (npts + 1023) / 1024;   // 1024 points per block (8 waves x 128)
    mlp_mfma<<<blocks, 512, 0, stream>>>(coords, frags, table, out, npts);
}

// Round 10
// 112.812 us; speedup vs baseline: 1.0748x; 1.0748x over previous
//
#include <hip/hip_runtime.h>

// ============================================================================
// 7-layer MLP (3->40x6->3, tanh) via f16 MFMA + dual-pipe tanh, 128 pts/wave.
//
// r9 postmortem: 4-tile version spilled (WRITE_SIZE 24.6->47 MB = ~23 MB
// scratch; VGPR=64): the backend targeted the 64-VGPR/8-wave tier and
// spilled the 48 Bf words. Fix (r10): amdgpu_waves_per_eu(4,4) pins the
// allocator at 4 waves/SIMD (128 VGPR budget), and D1-first ACT split drops
// peak pressure (compute 8-neuron M-tile D1, consume its 4 live words, THEN
// D0) -> ~110 live regs.
//
// r8 model (counter-fit): trans ops block the VALU port ~16cyc each. Per-tanh:
// exp path 37 cyc VALU; table path 10 cyc VALU + 5.8 cyc LDS (parallel pipe).
// SEXP=3 (12/40 neurons exp) + 4 B-tiles/wave balances VALU ~65us, LDS ~63us.
//
// MFMA layout contracts (gfx950 v_mfma_f32_32x32x16_f16), verified r3-r9:
//   A: row = lane&31, k = 8*(lane>>5)+i   B: col = lane&31, same k packing
//   D: col = lane&31, row = (reg&3) + 8*(reg>>2) + 4*(lane>>5)
// K-columns permuted (kappa) so D->B repack is in-lane. Verified identity:
// P := 4*(kap>>4) + ((kap&7)>>1) == Bf word index, all 40 neurons.
// Exp rows pre-scaled 2/ln2 (MFMA emits y; tanh = 1-2*rcp(1+2^y), exact).
// Table rows pre-scaled 32 + offset col 112 (MFMA emits u = (x+3.5)*32).
// Table: 225 entries, packed f16 {base,delta}/u32, 32-replica in LDS ->
// bank == lane&31 -> conflict-free (verified r7: conflicts 1.6e7 -> 0).
// ws = 36.7 KB total (r6 ERRATA: 64.6 KB overflowed ws -> poisoned table).
// ============================================================================

typedef _Float16 f16x8 __attribute__((ext_vector_type(8)));
typedef float    f32x16 __attribute__((ext_vector_type(16)));
typedef unsigned int u32x4 __attribute__((ext_vector_type(4)));

#define NFRAG  35        // L0: 2, L1..5: 6 each, L6: 3
#define TABN   225       // entries, domain [-3.5, 3.5], h = 1/32
#define TABREP 32        // LDS replication -> bank = lane&31, conflict-free
#define SEXP   3         // Bf words 0..2 (12 rows/layer) via exp path
#define INVH   32.0f
#define UOFF   112.0f    // 3.5*32, exact in f16
#define UMAX   223.999f
#define TABR   3.5f
#define EXPSC  2.8853900817779268f   // 2/ln(2)

// k-slot -> input neuron; -2 = bias, -3 = offset const, -1 = zero pad
__constant__ int INV[48] = {
     0,  1,  2,  3,   8,  9, 10, 11,   4,  5,  6,  7,  12, 13, 14, 15,
    16, 17, 18, 19,  24, 25, 26, 27,  20, 21, 22, 23,  28, 29, 30, 31,
    32, 33, 34, 35,  -1, -1, -1, -1,  36, 37, 38, 39,  -2, -3, -1, -1 };

// output neuron j -> k-slot (kappa); P(j) = 4*(kap>>4) + ((kap&7)>>1) = word
__constant__ int KAP[40] = {
     0,  1,  2,  3,   8,  9, 10, 11,   4,  5,  6,  7,  12, 13, 14, 15,
    16, 17, 18, 19,  24, 25, 26, 27,  20, 21, 22, 23,  28, 29, 30, 31,
    32, 33, 34, 35,  40, 41, 42, 43 };

__global__ void prep_frags(const float* __restrict__ W0, const float* __restrict__ b0,
                           const float* __restrict__ W1, const float* __restrict__ b1,
                           const float* __restrict__ W2, const float* __restrict__ b2,
                           const float* __restrict__ W3, const float* __restrict__ b3,
                           const float* __restrict__ W4, const float* __restrict__ b4,
                           const float* __restrict__ W5, const float* __restrict__ b5,
                           const float* __restrict__ W6, const float* __restrict__ b6,
                           unsigned short* __restrict__ frags,
                           unsigned* __restrict__ table)
{
    int tid = blockIdx.x * 256 + threadIdx.x;

    if (tid < NFRAG * 64) {
        int frag = tid >> 6, lane = tid & 63;

        int layer, mt, ch;
        if (frag < 2)       { layer = 0; mt = frag; ch = 0; }
        else if (frag < 32) { int t = frag - 2; layer = 1 + t / 6; int r = t % 6; mt = r / 3; ch = r % 3; }
        else                { layer = 6; mt = 0; ch = frag - 32; }

        const float* Ws[7] = { W0, W1, W2, W3, W4, W5, W6 };
        const float* bs[7] = { b0, b1, b2, b3, b4, b5, b6 };
        const float* W = Ws[layer];
        const float* b = bs[layer];
        const int fout = (layer == 6) ? 3 : 40;

        int jout  = mt * 32 + (lane & 31);
        int kbase = ch * 16 + (lane >> 5) * 8;

        unsigned short h[8];
        for (int i = 0; i < 8; ++i) {
            int k = kbase + i;
            float v = 0.0f;
            if (jout < fout) {
                int jin;
                if (layer == 0) jin = (k < 3) ? k : ((k == 3) ? -2 : ((k == 4) ? -3 : -1));
                else            jin = INV[k];
                bool ex = false;
                if (layer < 6) {
                    int kp = KAP[jout];
                    int P = 4 * (kp >> 4) + ((kp & 7) >> 1);   // == Bf word index
                    ex = (P < SEXP);
                }
                float scale = (layer == 6) ? 1.0f : (ex ? EXPSC : INVH);
                if (jin >= 0)       v = W[jin * fout + jout] * scale;
                else if (jin == -2) v = b[jout] * scale;
                else if (jin == -3) v = (layer == 6 || ex) ? 0.0f : UOFF;
            }
            _Float16 hv = (_Float16)v;
            h[i] = __builtin_bit_cast(unsigned short, hv);
        }
        unsigned short* dst = frags + frag * 512 + lane * 8;
        for (int i = 0; i < 8; ++i) dst[i] = h[i];
    }
    else if (tid < NFRAG * 64 + TABN) {
        int i = tid - NFRAG * 64;
        const float H = 1.0f / 32.0f;
        float x  = -TABR + (float)i * H;
        float t0 = tanhf(x);
        float t1 = tanhf(x + H);
        float MID = 0.5f * (1.0f + tanhf(TABR));
        float base = t0, delta = t1 - t0;
        if (i == 0)        { base = -MID; delta = t1 - base; }   // left clamp midpoint
        if (i == TABN - 2) { delta = MID - t0; }                 // right clamp midpoint
        unsigned short bb = __builtin_bit_cast(unsigned short, (_Float16)base);
        unsigned short dd = __builtin_bit_cast(unsigned short, (_Float16)delta);
        table[i] = (unsigned)bb | ((unsigned)dd << 16);          // unreplicated, 900 B
    }
}

__device__ __forceinline__ unsigned int pkf16(float a, float b) {
    return __builtin_bit_cast(unsigned int, __builtin_amdgcn_cvt_pkrtz(a, b));
}
__device__ __forceinline__ f32x16 zf() {
    f32x16 v;
    #pragma unroll
    for (int i = 0; i < 16; ++i) v[i] = 0.0f;
    return v;
}
__device__ __forceinline__ float exp2_fast(float y) {
#if __has_builtin(__builtin_amdgcn_exp2f)
    return __builtin_amdgcn_exp2f(y);
#else
    float e;
    asm("v_exp_f32 %0, %1" : "=v"(e) : "v"(y));
    return e;
#endif
}

#define MFMA __builtin_amdgcn_mfma_f32_32x32x16_f16

// second M-tile (neurons 32..39): only Db[0..3] are real rows -> consume
// immediately so D1 dies before D0 is computed (register-pressure fix, r10)
#define ACT_D1(Db, Bfx) do {                          \
    Bfx[8]  = tl2(Db[0],  Db[1]);                     \
    Bfx[9]  = tl2(Db[2],  Db[3]);                     \
    Bfx[10] = PK11;                                   \
    Bfx[11] = 0u;                                     \
} while (0)

// first M-tile: words 0..2 exp path, 3..7 table path
#define ACT_D0(Da, Bfx) do {                          \
    Bfx[0]  = pkf16(te(Da[0]),  te(Da[1]));           \
    Bfx[1]  = pkf16(te(Da[2]),  te(Da[3]));           \
    Bfx[2]  = pkf16(te(Da[4]),  te(Da[5]));           \
    Bfx[3]  = tl2(Da[6],  Da[7]);                     \
    Bfx[4]  = tl2(Da[8],  Da[9]);                     \
    Bfx[5]  = tl2(Da[10], Da[11]);                    \
    Bfx[6]  = tl2(Da[12], Da[13]);                    \
    Bfx[7]  = tl2(Da[14], Da[15]);                    \
} while (0)

// one 32-point tile of layer 0 (K chunk 0: coords + bias + offset cols)
#define L0_TILE(Bfx) do {                             \
    f16x8 bb = BFx(Bfx, 0);                           \
    {                                                 \
        f32x16 D1 = MFMA(F1, bb, CZ, 0, 0, 0);        \
        ACT_D1(D1, Bfx);                              \
    }                                                 \
    {                                                 \
        f32x16 D0 = MFMA(F0, bb, CZ, 0, 0, 0);        \
        ACT_D0(D0, Bfx);                              \
    }                                                 \
} while (0)

// one 32-point tile of a hidden layer (D1 first, then D0)
#define HID_TILE(Bfx) do {                            \
    f16x8 B0 = BFx(Bfx, 0), B1 = BFx(Bfx, 1), B2 = BFx(Bfx, 2); \
    {                                                 \
        f32x16 D1 = MFMA(F3, B0, CZ, 0, 0, 0);        \
        D1 = MFMA(F4, B1, D1, 0, 0, 0);               \
        D1 = MFMA(F5, B2, D1, 0, 0, 0);               \
        ACT_D1(D1, Bfx);                              \
    }                                                 \
    {                                                 \
        f32x16 D0 = MFMA(F0, B0, CZ, 0, 0, 0);        \
        D0 = MFMA(F1, B1, D0, 0, 0, 0);               \
        D0 = MFMA(F2, B2, D0, 0, 0, 0);               \
        ACT_D0(D0, Bfx);                              \
    }                                                 \
} while (0)

// one 32-point tile of the final layer (rows 0..2, lane<32)
#define FIN_TILE(Bfx, pX, vX) do {                    \
    f32x16 D0 = MFMA(F0, BFx(Bfx, 0), CZ, 0, 0, 0);   \
    D0 = MFMA(F1, BFx(Bfx, 1), D0, 0, 0, 0);          \
    D0 = MFMA(F2, BFx(Bfx, 2), D0, 0, 0, 0);          \
    if (lane < 32 && vX) {                            \
        out[(pX) * 3 + 0] = D0[0];                    \
        out[(pX) * 3 + 1] = D0[1];                    \
        out[(pX) * 3 + 2] = D0[2];                    \
    }                                                 \
} while (0)

__global__ __attribute__((amdgpu_waves_per_eu(4, 4)))
__launch_bounds__(512) void mlp_mfma(const float* __restrict__ coords,
                                     const unsigned short* __restrict__ frags,
                                     const unsigned* __restrict__ gtab,
                                     float* __restrict__ out, int npts)
{
    __shared__ __align__(16) unsigned short sf[NFRAG * 512];   // 35840 B
    __shared__ __align__(16) unsigned stab[TABN * TABREP];     // 28800 B
    {
        const u32x4* s1 = (const u32x4*)frags; u32x4* d1 = (u32x4*)sf;
        for (int i = threadIdx.x; i < NFRAG * 64; i += 512) d1[i] = s1[i];
        // replicate 32x from the unreplicated global table (L2-resident)
        for (int i = threadIdx.x; i < TABN * TABREP; i += 512) stab[i] = gtab[i >> 5];
    }
    __syncthreads();

    const int lane = threadIdx.x & 63;
    const int wid  = threadIdx.x >> 6;
    const int pA   = (blockIdx.x * 8 + wid) * 128 + (lane & 31);
    const int pB   = pA + 32;
    const int pC   = pA + 64;
    const int pD   = pA + 96;
    const bool vA = (pA < npts), vB = (pB < npts), vC = (pC < npts), vD = (pD < npts);

    const unsigned int PK11 = pkf16(1.0f, 1.0f);
    const unsigned* __restrict__ tb = stab + (lane & 31);   // bank = lane&31 always
    const f32x16 CZ = zf();

    // table path: u = (x+3.5)*32 from MFMA; {base,delta} packed f16 in u32.
    auto tl2 = [&](float ua, float ub) -> unsigned {
        ua = __builtin_amdgcn_fmed3f(ua, 0.0f, UMAX);
        ub = __builtin_amdgcn_fmed3f(ub, 0.0f, UMAX);
        float fa = __builtin_amdgcn_fractf(ua);
        float fb = __builtin_amdgcn_fractf(ub);
        unsigned ea = tb[(unsigned)ua * TABREP];   // ds_read_b32, conflict-free
        unsigned eb = tb[(unsigned)ub * TABREP];
        unsigned r;
        asm("v_fma_mixlo_f16 %0, %1, %2, %2 op_sel:[0,1,0] op_sel_hi:[0,1,1]"
            : "=v"(r) : "v"(fa), "v"(ea));
        asm("v_fma_mixhi_f16 %0, %1, %2, %2 op_sel:[0,1,0] op_sel_hi:[0,1,1]"
            : "+v"(r) : "v"(fb), "v"(eb));
        return r;
    };
    // exp path: y = 2x/ln2 from MFMA; tanh = 1 - 2/(1+2^y). Exact, no clamp.
    auto te = [&](float y) -> float {
        float e = exp2_fast(y);
        float r = __builtin_amdgcn_rcpf(e + 1.0f);
        return __builtin_fmaf(-2.0f, r, 1.0f);
    };

    unsigned int BfA[12], BfB[12], BfC[12], BfD[12];
    {
        float a0 = 0.f, a1 = 0.f, a2 = 0.f, b0 = 0.f, b1 = 0.f, b2 = 0.f;
        float c0 = 0.f, c1 = 0.f, c2 = 0.f, d0 = 0.f, d1 = 0.f, d2 = 0.f;
        if (vA) { a0 = coords[pA * 3]; a1 = coords[pA * 3 + 1]; a2 = coords[pA * 3 + 2]; }
        if (vB) { b0 = coords[pB * 3]; b1 = coords[pB * 3 + 1]; b2 = coords[pB * 3 + 2]; }
        if (vC) { c0 = coords[pC * 3]; c1 = coords[pC * 3 + 1]; c2 = coords[pC * 3 + 2]; }
        if (vD) { d0 = coords[pD * 3]; d1 = coords[pD * 3 + 1]; d2 = coords[pD * 3 + 2]; }
        BfA[0] = pkf16(a0, a1); BfA[1] = pkf16(a2, 1.0f);
        BfB[0] = pkf16(b0, b1); BfB[1] = pkf16(b2, 1.0f);
        BfC[0] = pkf16(c0, c1); BfC[1] = pkf16(c2, 1.0f);
        BfD[0] = pkf16(d0, d1); BfD[1] = pkf16(d2, 1.0f);
        BfA[2] = BfB[2] = BfC[2] = BfD[2] = pkf16(1.0f, 0.0f);
        BfA[3] = BfB[3] = BfC[3] = BfD[3] = 0u;
    }

    auto AF = [&](int f) -> f16x8 {
        return ((const f16x8*)sf)[f * 64 + lane];
    };
    auto BFx = [&](const unsigned (&B)[12], int c) -> f16x8 {
        u32x4 t = { B[4 * c + 0], B[4 * c + 1], B[4 * c + 2], B[4 * c + 3] };
        return __builtin_bit_cast(f16x8, t);
    };

    f16x8 F0, F1, F2, F3, F4, F5;

    // ---- layer 0
    F0 = AF(0); F1 = AF(1);
    L0_TILE(BfA); L0_TILE(BfB); L0_TILE(BfC); L0_TILE(BfD);

    // ---- hidden layers 1..5
    #pragma unroll
    for (int l = 1; l <= 5; ++l) {
        const int fb = 2 + (l - 1) * 6;
        F0 = AF(fb + 0); F1 = AF(fb + 1); F2 = AF(fb + 2);
        F3 = AF(fb + 3); F4 = AF(fb + 4); F5 = AF(fb + 5);
        HID_TILE(BfA); HID_TILE(BfB); HID_TILE(BfC); HID_TILE(BfD);
    }

    // ---- layer 6: [40] -> [3], true scale, no tanh
    F0 = AF(32); F1 = AF(33); F2 = AF(34);
    FIN_TILE(BfA, pA, vA);
    FIN_TILE(BfB, pB, vB);
    FIN_TILE(BfC, pC, vC);
    FIN_TILE(BfD, pD, vD);
}

extern "C" void kernel_launch(void* const* d_in, const int* in_sizes, int n_in,
                              void* d_out, int out_size, void* d_ws, size_t ws_size,
                              hipStream_t stream)
{
    const float* coords = (const float*)d_in[0];
    const float* W0 = (const float*)d_in[1];  const float* b0 = (const float*)d_in[2];
    const float* W1 = (const float*)d_in[3];  const float* b1 = (const float*)d_in[4];
    const float* W2 = (const float*)d_in[5];  const float* b2 = (const float*)d_in[6];
    const float* W3 = (const float*)d_in[7];  const float* b3 = (const float*)d_in[8];
    const float* W4 = (const float*)d_in[9];  const float* b4 = (const float*)d_in[10];
    const float* W5 = (const float*)d_in[11]; const float* b5 = (const float*)d_in[12];
    const float* W6 = (const float*)d_in[13]; const float* b6 = (const float*)d_in[14];
    float* out = (float*)d_out;

    unsigned short* frags = (unsigned short*)d_ws;                      // 35840 B
    unsigned* table = (unsigned*)((char*)d_ws + NFRAG * 1024);          // 900 B

    const int npts = in_sizes[0] / 3;

    const int prep_threads = NFRAG * 64 + TABN;
    prep_frags<<<(prep_threads + 255) / 256, 256, 0, stream>>>(
        W0, b0, W1, b1, W2, b2, W3, b3, W4, b4, W5, b5, W6, b6, frags, table);

    const int blocks = (npts + 1023) / 1024;   // 1024 points per block (8 waves x 128)
    mlp_mfma<<<blocks, 512, 0, stream>>>(coords, frags, table, out, npts);
}